// Round 1
// baseline (777.737 us; speedup 1.0000x reference)
//
#include <hip/hip_runtime.h>
#include <hip/hip_bf16.h>
#include <cmath>

// Problem constants (from reference): N=100000, D=512, H1=16, C=40, NNZ=3.2M
#define DD 512
#define HH 16
#define CC 40

// ---------------------------------------------------------------------------
// K1: X1 = H @ W1   (N x 512) @ (512 x 16) -> (N x 16)
// Memory-bound on H. W1 staged in LDS (32 KB), wave-uniform broadcast reads.
// 4 rows per thread, float4 loads of H.
// ---------------------------------------------------------------------------
__global__ __launch_bounds__(256) void k_gemm1(const float* __restrict__ Hm,
                                               const float* __restrict__ W1,
                                               float* __restrict__ X1,
                                               int nrows) {
    __shared__ float w1s[DD * HH];  // 32 KB
    for (int i = (int)threadIdx.x; i < DD * HH / 4; i += 256)
        reinterpret_cast<float4*>(w1s)[i] = reinterpret_cast<const float4*>(W1)[i];
    __syncthreads();

    const int base = blockIdx.x * 1024 + (int)threadIdx.x;
    int   row[4];
    bool  ok[4];
#pragma unroll
    for (int r = 0; r < 4; ++r) { row[r] = base + r * 256; ok[r] = (row[r] < nrows); }

    float acc[4][HH];
#pragma unroll
    for (int r = 0; r < 4; ++r)
#pragma unroll
        for (int j = 0; j < HH; ++j) acc[r][j] = 0.f;

    for (int k4 = 0; k4 < DD; k4 += 4) {
        float h[4][4];
#pragma unroll
        for (int r = 0; r < 4; ++r) {
            if (ok[r]) {
                float4 hv = *reinterpret_cast<const float4*>(&Hm[(size_t)row[r] * DD + k4]);
                h[r][0] = hv.x; h[r][1] = hv.y; h[r][2] = hv.z; h[r][3] = hv.w;
            } else {
                h[r][0] = h[r][1] = h[r][2] = h[r][3] = 0.f;
            }
        }
#pragma unroll
        for (int kk = 0; kk < 4; ++kk) {
            const float* wr = &w1s[(k4 + kk) * HH];
#pragma unroll
            for (int j = 0; j < HH; ++j) {
                float w = wr[j];
#pragma unroll
                for (int r = 0; r < 4; ++r) acc[r][j] += h[r][kk] * w;
            }
        }
    }

#pragma unroll
    for (int r = 0; r < 4; ++r) {
        if (!ok[r]) continue;
        float4* outp = reinterpret_cast<float4*>(&X1[(size_t)row[r] * HH]);
#pragma unroll
        for (int j4 = 0; j4 < 4; ++j4)
            outp[j4] = make_float4(acc[r][j4 * 4 + 0], acc[r][j4 * 4 + 1],
                                   acc[r][j4 * 4 + 2], acc[r][j4 * 4 + 3]);
    }
}

// ---------------------------------------------------------------------------
// K2 / K3: scatter spmm. One thread per (edge, feature j of 16).
// S[rows[e]][j] += vals[e] * f(X[cols[e]][j])
// where f is identity (layer 1) or relu(x + b1[j]) (layer 2, fused).
// ---------------------------------------------------------------------------
__global__ __launch_bounds__(256) void k_spmm(const int* __restrict__ rows,
                                              const int* __restrict__ cols,
                                              const float* __restrict__ vals,
                                              const float* __restrict__ X,
                                              float* __restrict__ S,
                                              const float* __restrict__ bias,
                                              int relu_in, int nnz) {
    long long idx = (long long)blockIdx.x * 256 + threadIdx.x;
    if (idx >= (long long)nnz * HH) return;
    int e = (int)(idx >> 4);
    int j = (int)(idx & 15);
    int c = cols[e];
    int r = rows[e];
    float v = vals[e];
    float x = X[(size_t)c * HH + j];
    if (relu_in) {
        x = x + bias[j];
        x = x > 0.f ? x : 0.f;
    }
    atomicAdd(&S[(size_t)r * HH + j], v * x);
}

// ---------------------------------------------------------------------------
// K4: out = log_softmax(relu(T @ W2 + b2)).  One thread per row.
// T: N x 16, W2: 16 x 40 (row-major), out: N x 40.
// ---------------------------------------------------------------------------
__global__ __launch_bounds__(256) void k_out(const float* __restrict__ T,
                                             const float* __restrict__ W2,
                                             const float* __restrict__ b2,
                                             float* __restrict__ out,
                                             int nrows) {
    __shared__ float w2s[HH * CC];
    __shared__ float b2s[CC];
    for (int i = (int)threadIdx.x; i < HH * CC; i += 256) w2s[i] = W2[i];
    if (threadIdx.x < CC) b2s[threadIdx.x] = b2[threadIdx.x];
    __syncthreads();

    int row = blockIdx.x * 256 + (int)threadIdx.x;
    if (row >= nrows) return;

    float t[HH];
#pragma unroll
    for (int k4 = 0; k4 < HH; k4 += 4) {
        float4 tv = *reinterpret_cast<const float4*>(&T[(size_t)row * HH + k4]);
        t[k4] = tv.x; t[k4 + 1] = tv.y; t[k4 + 2] = tv.z; t[k4 + 3] = tv.w;
    }

    float y[CC];
#pragma unroll
    for (int j = 0; j < CC; ++j) {
        float a = b2s[j];
#pragma unroll
        for (int k = 0; k < HH; ++k) a += t[k] * w2s[k * CC + j];
        y[j] = a > 0.f ? a : 0.f;
    }

    float m = y[0];
#pragma unroll
    for (int j = 1; j < CC; ++j) m = fmaxf(m, y[j]);
    float s = 0.f;
#pragma unroll
    for (int j = 0; j < CC; ++j) s += __expf(y[j] - m);
    float ls = __logf(s) + m;

    float4* op = reinterpret_cast<float4*>(&out[(size_t)row * CC]);
#pragma unroll
    for (int j4 = 0; j4 < CC / 4; ++j4)
        op[j4] = make_float4(y[j4 * 4 + 0] - ls, y[j4 * 4 + 1] - ls,
                             y[j4 * 4 + 2] - ls, y[j4 * 4 + 3] - ls);
}

// ---------------------------------------------------------------------------
// Inputs (setup_inputs order):
//  0: H      (N*512 f32)     1: A_vals (NNZ f32)   2: W1 (512*16 f32)
//  3: b1     (16 f32)        4: W2     (16*40 f32) 5: b2 (40 f32)
//  6: A_rows (NNZ i32)       7: A_cols (NNZ i32)
// Output: N*40 f32 (log_softmax)
// ---------------------------------------------------------------------------
extern "C" void kernel_launch(void* const* d_in, const int* in_sizes, int n_in,
                              void* d_out, int out_size, void* d_ws, size_t ws_size,
                              hipStream_t stream) {
    const float* Hm   = (const float*)d_in[0];
    const float* Av   = (const float*)d_in[1];
    const float* W1   = (const float*)d_in[2];
    const float* b1   = (const float*)d_in[3];
    const float* W2   = (const float*)d_in[4];
    const float* b2   = (const float*)d_in[5];
    const int*   Ar   = (const int*)d_in[6];
    const int*   Ac   = (const int*)d_in[7];
    float*       out  = (float*)d_out;

    const int N   = in_sizes[0] / DD;
    const int NNZ = in_sizes[6];

    float* X1 = (float*)d_ws;           // N*16
    float* S1 = X1 + (size_t)N * HH;    // N*16
    float* T  = S1 + (size_t)N * HH;    // N*16

    // zero the two atomic accumulators (S1, T adjacent)
    hipMemsetAsync(S1, 0, (size_t)2 * N * HH * sizeof(float), stream);

    // K1: X1 = H @ W1
    int g1 = (N + 1023) / 1024;
    k_gemm1<<<g1, 256, 0, stream>>>(Hm, W1, X1, N);

    // K2: S1 = A @ X1   (scatter atomics)
    long long work = (long long)NNZ * HH;
    int g2 = (int)((work + 255) / 256);
    k_spmm<<<g2, 256, 0, stream>>>(Ar, Ac, Av, X1, S1, b1, /*relu_in=*/0, NNZ);

    // K3: T = A @ relu(S1 + b1)   (bias+relu fused into gather)
    k_spmm<<<g2, 256, 0, stream>>>(Ar, Ac, Av, S1, T, b1, /*relu_in=*/1, NNZ);

    // K4: out = log_softmax(relu(T @ W2 + b2))
    int g4 = (N + 255) / 256;
    k_out<<<g4, 256, 0, stream>>>(T, W2, b2, out, N);
}